// Round 5
// baseline (292.646 us; speedup 1.0000x reference)
//
#include <hip/hip_runtime.h>
#include <hip/hip_bf16.h>
#include <math.h>

// Problem dims (fixed by reference)
#define BB 64
#define SS 200
#define TT 32
#define VV 50000
#define EE 128
#define CC 128
#define HH 100
#define G3 300           // 3*H
#define OUTD 104
#define NTREE (BB*SS)    // 12800

typedef __attribute__((ext_vector_type(4))) float f32x4;
typedef _Float16 f16x8 __attribute__((ext_vector_type(8)));

#define L2E  1.4426950408889634f
#define NL2E (-1.4426950408889634f)
#define TL2E 2.8853900817779268f

// LDS-only barrier: waits ds-ops (lgkmcnt) but does NOT drain vmcnt, so in-flight
// global prefetch loads stay outstanding across the barrier (waited at use).
#define BAR() asm volatile("s_waitcnt lgkmcnt(0)\n\ts_barrier" ::: "memory")

// Workspace byte offsets
//   wl    @ 0        : 32768 B   (k1 W_lin fragment image, fp16)
//   k2b   @ 32768    : 163840 B  (k2 W_ih fragment image, fp16)
//   thi   @ 196608   : 3276800 B (tree_vec, fp16)
//   k3b   @ 3473408  : 196608 B  (k3 prescaled W_hh fragment image, fp16)
//   gx    @ 3670016  : 30720000 B (fp32)  -- ends at 34.39 MB < ws
//   emb16 @ 3670016  : 12800000 B -- ALIASES gx: k0 writes it, k1 reads it,
//                                   k2 overwrites gx only after k1 completes.
//   pool  @ 0        : 51200 B   -- aliases wl/k2b; k3 writes it AFTER k2 read them.

// ---------------- K0: weight-fragment images + fp16 embedding image (idempotent)
__global__ __launch_bounds__(256) void k0_prep(const float* __restrict__ w_lin,
                                               const float* __restrict__ w_ih_f,
                                               const float* __restrict__ w_ih_b,
                                               const float* __restrict__ w_hh_f,
                                               const float* __restrict__ w_hh_b,
                                               const float* __restrict__ emb,
                                               _Float16* __restrict__ wl,
                                               _Float16* __restrict__ k2b,
                                               _Float16* __restrict__ k3b,
                                               _Float16* __restrict__ emb16) {
    const int tid  = threadIdx.x;
    const int wave = tid >> 6;
    const int lane = tid & 63;
    const int r = lane & 15;
    const int q = lane >> 4;
    if (blockIdx.x == 0) {
        // k1 image: wave w, lane(r,q), nt, kt -> W_lin[n=w*32+nt*16+r][k=kt*32+q*8 ..+8]
#pragma unroll
        for (int nt = 0; nt < 2; ++nt)
#pragma unroll
            for (int kt = 0; kt < 4; ++kt) {
                const int n = wave * 32 + nt * 16 + r;
                const float* src = w_lin + (long)n * EE + kt * 32 + q * 8;
                f16x8 f;
#pragma unroll
                for (int e = 0; e < 8; ++e) f[e] = (_Float16)src[e];
                *(f16x8*)&wl[(size_t)((((wave * 2 + nt) * 4 + kt) * 64) + lane) * 8] = f;
            }
    } else if (blockIdx.x <= 10) {
        // k2 image: nb, wave w, lane(r,q), kt -> W_ih[padded n = nb*64+w*16+r][k=kt*32+q*8]
        const int nb = blockIdx.x - 1;           // 0..9
        const int n = nb * 64 + wave * 16 + r;
        const int dir = (n >= 320) ? 1 : 0;
        const int j = n - dir * 320;
        const int jj = (j < G3) ? j : 0;         // pad rows clamped (results discarded)
        const float* w = dir ? w_ih_b : w_ih_f;
#pragma unroll
        for (int kt = 0; kt < 4; ++kt) {
            const float* src = w + (long)jj * EE + kt * 32 + q * 8;
            f16x8 f;
#pragma unroll
            for (int e = 0; e < 8; ++e) f[e] = (_Float16)src[e];
            *(f16x8*)&k2b[(size_t)((((nb * 4 + wave) * 4 + kt) * 64) + lane) * 8] = f;
        }
    } else if (blockIdx.x <= 12) {
        // k3 image, PRESCALED: dir d, wave-slot w (channels 25w..25w+24).
        // 6 tiles: t in 0..2 -> gate t of within-wave channel r; t in 3..5 -> gate
        // t-3 of channel 16+r (valid iff <25). Gates r,z scaled by -log2(e); gate n
        // scaled by +2*log2(e) (folds the exp2 arguments of sigmoid/tanh).
        const int d = blockIdx.x - 11;           // 0..1
        const float* whh = d ? w_hh_b : w_hh_f;
#pragma unroll
        for (int t = 0; t < 6; ++t) {
            const int gate = (t < 3) ? t : t - 3;
            const int ch   = (t < 3) ? r : 16 + r;
            const bool nv  = (ch < 25);
            const int row  = gate * HH + wave * 25 + (nv ? ch : 0);
            const float sc = (gate == 2) ? TL2E : NL2E;
#pragma unroll
            for (int kt = 0; kt < 4; ++kt) {
                f16x8 f;
#pragma unroll
                for (int e = 0; e < 8; ++e) {
                    const int k = kt * 32 + q * 8 + e;
                    f[e] = (_Float16)((nv && k < HH) ? sc * whh[row * HH + k] : 0.f);
                }
                *(f16x8*)&k3b[(size_t)((((d * 4 + wave) * 6 + t) * 4 + kt) * 64 + lane) * 8] = f;
            }
        }
    } else {
        // fp16 embedding image: 50000*128 = 6,400,000 elems = 3125 blocks * 2048
        const long base = (long)(blockIdx.x - 13) * 2048 + (long)tid * 8;
        if (base < (long)VV * EE) {
            const float4* s = (const float4*)(emb + base);
            const float4 v0 = s[0], v1 = s[1];
            f16x8 f;
            f[0] = (_Float16)v0.x; f[1] = (_Float16)v0.y;
            f[2] = (_Float16)v0.z; f[3] = (_Float16)v0.w;
            f[4] = (_Float16)v1.x; f[5] = (_Float16)v1.y;
            f[6] = (_Float16)v1.z; f[7] = (_Float16)v1.w;
            *(f16x8*)&emb16[base] = f;
        }
    }
}

// ---------------- K1 (fp16 MFMA): embed-gather (fp16) -> GEMM vs W_lin^T -> bias -> tree-sum -> maxpool
#define K1_TPI 2
#define AROWS (K1_TPI*TT)        // 64
#define LDA 136                  // fp16/row: 128 + 8 pad
#define LDC 132                  // fp32/row: 128 + 4 pad

__global__ __launch_bounds__(256) void k1_mfma(const int* __restrict__ tok,
                                               const _Float16* __restrict__ emb16,
                                               const _Float16* __restrict__ wl,
                                               const float* __restrict__ b_lin,
                                               _Float16* __restrict__ thi) {
    __shared__ __align__(16) _Float16 A_sh[AROWS * LDA];   // 17408 B
    __shared__ __align__(16) float C_sh[AROWS * LDC];      // 33792 B
    __shared__ int tok_sh[AROWS];

    const int tid  = threadIdx.x;
    const int wave = tid >> 6;
    const int lane = tid & 63;
    const int r = lane & 15;
    const int q = lane >> 4;

    // ---- B fragments: 8 coalesced 16B loads from the prebuilt image (no cvt VALU)
    f16x8 bfrag[2][4];
    float bias[2];
#pragma unroll
    for (int nt = 0; nt < 2; ++nt) {
        bias[nt] = b_lin[wave * 32 + nt * 16 + r];
#pragma unroll
        for (int kt = 0; kt < 4; ++kt)
            bfrag[nt][kt] = *(const f16x8*)&wl[(size_t)((((wave * 2 + nt) * 4 + kt) * 64) + lane) * 8];
    }

    const int tree0 = blockIdx.x * K1_TPI;
    if (tid < AROWS) tok_sh[tid] = tok[tree0 * TT + tid];
    __syncthreads();

    // ---- gather fp16 embeddings -> LDS (pure 16B copies, half the global traffic)
#pragma unroll
    for (int i = 0; i < 4; ++i) {
        const int idx = tid + i * 256;       // 0..1023
        const int row = idx >> 4;            // 64 rows
        const int p   = idx & 15;            // 16 x f16x8 = 128 elems
        const f16x8 v = *(const f16x8*)&emb16[(long)tok_sh[row] * EE + p * 8];
        *(f16x8*)&A_sh[row * LDA + p * 8] = v;
    }
    __syncthreads();

    f32x4 acc[4][2];
#pragma unroll
    for (int mt = 0; mt < 4; ++mt)
#pragma unroll
        for (int nt = 0; nt < 2; ++nt) acc[mt][nt] = (f32x4)(0.f);

#pragma unroll
    for (int mt = 0; mt < 4; ++mt) {
        const int m = mt * 16 + r;
        f16x8 afrag[4];
#pragma unroll
        for (int kt = 0; kt < 4; ++kt)
            afrag[kt] = *(const f16x8*)&A_sh[m * LDA + kt * 32 + q * 8];
#pragma unroll
        for (int nt = 0; nt < 2; ++nt)
#pragma unroll
            for (int kt = 0; kt < 4; ++kt)
                acc[mt][nt] = __builtin_amdgcn_mfma_f32_16x16x32_f16(
                    afrag[kt], bfrag[nt][kt], acc[mt][nt], 0, 0, 0);
    }

#pragma unroll
    for (int mt = 0; mt < 4; ++mt)
#pragma unroll
        for (int nt = 0; nt < 2; ++nt) {
            const int col = wave * 32 + nt * 16 + r;
#pragma unroll
            for (int reg = 0; reg < 4; ++reg) {
                const int row = mt * 16 + q * 4 + reg;
                C_sh[row * LDC + col] = acc[mt][nt][reg] + bias[nt];
            }
        }
    __syncthreads();

    // ---- tree-sum + maxpool in registers (descending index = topological order)
    {
        const int t = tid >> 7;
        const int j = tid & 127;
        const float* base = &C_sh[(t * TT) * LDC + j];
        float v[TT];
#pragma unroll
        for (int n = 0; n < TT; ++n) v[n] = base[n * LDC];
        float mx = -1e30f;
#pragma unroll
        for (int n = TT - 1; n >= 1; --n) {
            mx = fmaxf(mx, v[n]);
            v[(n - 1) >> 1] += v[n];
        }
        mx = fmaxf(mx, v[0]);
        thi[(size_t)(tree0 + t) * CC + j] = (_Float16)mx;   // fp32 sums, one fp16 round
    }
}

// ---------------- K2 (fp16 MFMA): gx[dir][m=b*S+s][300] = X @ W_ih^T + b_ih
__global__ __launch_bounds__(256) void k2_mfma(const _Float16* __restrict__ thi,
                                               const _Float16* __restrict__ k2b,
                                               const float* __restrict__ b_ih_f,
                                               const float* __restrict__ b_ih_b,
                                               float* __restrict__ gx) {
    __shared__ __align__(16) _Float16 Ah[32 * LDA];   // 8704 B

    const int tid  = threadIdx.x;
    const int wave = tid >> 6;
    const int lane = tid & 63;
    const int r = lane & 15;
    const int q = lane >> 4;

    const int nb = blockIdx.x % 10;
    const int mb = blockIdx.x / 10;
    const int m0 = mb * 32;
    const int n0 = nb * 64;

    // stage A: 32 rows x 128 fp16 = 512 f16x8; 2 per thread (copy, no conversion)
#pragma unroll
    for (int i = 0; i < 2; ++i) {
        const int idx = tid + i * 256;
        const int row = idx >> 4;
        const int p   = idx & 15;
        f16x8 v = *(const f16x8*)&thi[(size_t)(m0 + row) * CC + p * 8];
        *(f16x8*)&Ah[row * LDA + p * 8] = v;
    }
    // B fragments: 4 coalesced 16B loads
    f16x8 bh[4];
#pragma unroll
    for (int kt = 0; kt < 4; ++kt)
        bh[kt] = *(const f16x8*)&k2b[(size_t)((((nb * 4 + wave) * 4 + kt) * 64) + lane) * 8];
    __syncthreads();

    f32x4 acc[2];
    acc[0] = (f32x4)(0.f); acc[1] = (f32x4)(0.f);
#pragma unroll
    for (int mt = 0; mt < 2; ++mt) {
        const int m = mt * 16 + r;
#pragma unroll
        for (int kt = 0; kt < 4; ++kt) {
            f16x8 a = *(const f16x8*)&Ah[m * LDA + kt * 32 + q * 8];
            acc[mt] = __builtin_amdgcn_mfma_f32_16x16x32_f16(a, bh[kt], acc[mt], 0, 0, 0);
        }
    }

    const int ng  = n0 + wave * 16 + r;
    const int dir = (ng >= 320) ? 1 : 0;
    const int j   = ng - dir * 320;
    const bool valid = (j < G3);
    const float bias = valid ? (dir ? b_ih_b[j] : b_ih_f[j]) : 0.f;
    float* gxd = gx + (long)dir * NTREE * G3;
    if (valid) {
#pragma unroll
        for (int mt = 0; mt < 2; ++mt)
#pragma unroll
            for (int reg = 0; reg < 4; ++reg) {
                const int m = m0 + mt * 16 + q * 4 + reg;
                gxd[(long)m * G3 + j] = acc[mt][reg] + bias;
            }
    }
}

// ---------------- K3 v10: v7 structure + v8's 6-tile self-aligned gates + prescale.
// Proven parts only: 128 blocks x 4 waves (1 chain/block, weights fit in VGPR:
// bf[6][4]=96), one 4-wave barrier per step, 4-deep NAMED gx prefetch (v7-verified).
// New vs v7: no ds_bpermute/q-select (v8-verified 6-tile mapping, VALU 18->9) and
// exp2-argument prescale folded into the k0 weight image + prefetch FMAs, cutting
// the serial activation chain to ~11 ops.
__global__ __launch_bounds__(256, 1) void k3_gru(const float* __restrict__ gx,
                                                 const _Float16* __restrict__ k3b,
                                                 const float* __restrict__ b_hh_f,
                                                 const float* __restrict__ b_hh_b,
                                                 float* __restrict__ pool) {
    const int bid = blockIdx.x;   // 0..127
    const int dir = bid & 1;
    const int b   = bid >> 1;
    const int tid = threadIdx.x;
    const int wave = tid >> 6;
    const int lane = tid & 63;
    const int r = lane & 15;
    const int q = lane >> 4;

    const float* b_hh = dir ? b_hh_b : b_hh_f;

    __shared__ __align__(16) _Float16 h_sh[2][128];

    // B fragments: 24 coalesced 16B loads from the prebuilt PRESCALED image
    const int dw = dir * 4 + wave;
    f16x8 bf[6][4];
#pragma unroll
    for (int t = 0; t < 6; ++t)
#pragma unroll
        for (int kt = 0; kt < 4; ++kt)
            bf[t][kt] = *(const f16x8*)&k3b[(size_t)(((dw * 6 + t) * 4 + kt) * 64 + lane) * 8];

    const int m = lane;
    const int c = wave * 25 + m;
    const bool act  = (m < 25);
    const bool lo16 = (m < 16);
    // prescaled biases: r/z folded into prefetch (brc/bzc); n kept separate (bnc)
    float brc = 0.f, bzc = 0.f, bnc = 0.f;
    if (act) {
        brc = NL2E * b_hh[c];
        bzc = NL2E * b_hh[HH + c];
        bnc = TL2E * b_hh[2 * HH + c];
    }

    if (tid < 128) { h_sh[0][tid] = (_Float16)0.f; h_sh[1][tid] = (_Float16)0.f; }

    const int sstep = dir ? -1 : 1;
    const int s0 = dir ? (SS - 1) : 0;
    const float* gp = gx + (long)dir * NTREE * G3 + (long)b * SS * G3 + c;

    // 4-deep prefetch, NAMED buffers; exp2-arg prescale folded in (off critical path)
    float pxr[4], pxz[4], pxn[4];
    if (act) {
#pragma unroll
        for (int j = 0; j < 4; ++j) {
            const long off = (long)(s0 + j * sstep) * G3;
            pxr[j] = __builtin_fmaf(gp[off], NL2E, brc);
            pxz[j] = __builtin_fmaf(gp[off + HH], NL2E, bzc);
            pxn[j] = gp[off + 2 * HH] * TL2E;
        }
    }
    float hj = 0.f, hmax = -1e30f;
    __syncthreads();

    int s = s0;
    for (int t0 = 0; t0 < SS; t0 += 4) {
#pragma unroll
        for (int j = 0; j < 4; ++j) {
            const int p = j & 1;             // (t0+j)&1, t0 multiple of 4

            f16x8 a[4];
#pragma unroll
            for (int kt = 0; kt < 4; ++kt)
                a[kt] = *(const f16x8*)&h_sh[p][kt * 32 + q * 8];

            // split-K: two parallel depth-2 chains per tile, 24 MFMA total
            f32x4 accA[6], accB[6];
#pragma unroll
            for (int i = 0; i < 6; ++i) {
                accA[i] = (f32x4)(0.f);
                accB[i] = (f32x4)(0.f);
                accA[i] = __builtin_amdgcn_mfma_f32_16x16x32_f16(a[0], bf[i][0], accA[i], 0, 0, 0);
                accB[i] = __builtin_amdgcn_mfma_f32_16x16x32_f16(a[2], bf[i][2], accB[i], 0, 0, 0);
                accA[i] = __builtin_amdgcn_mfma_f32_16x16x32_f16(a[1], bf[i][1], accA[i], 0, 0, 0);
                accB[i] = __builtin_amdgcn_mfma_f32_16x16x32_f16(a[3], bf[i][3], accB[i], 0, 0, 0);
            }
            const float G0 = accA[0][0] + accB[0][0];
            const float G1 = accA[1][0] + accB[1][0];
            const float G2 = accA[2][0] + accB[2][0];
            const float G3v = accA[3][0] + accB[3][0];
            const float G4 = accA[4][0] + accB[4][0];
            const float G5 = accA[5][0] + accB[5][0];
            // lane m<16: gates of channel m via tiles 0-2; m in 16..24: tiles 3-5
            const float ghr = lo16 ? G0 : G3v;
            const float ghz = lo16 ? G1 : G4;
            const float ghn = lo16 ? G2 : G5;

            if (act) {
                // rg = sigmoid(xr+ghr+br) with exp2-args prebuilt:
                const float rg = __builtin_amdgcn_rcpf(1.f + __builtin_amdgcn_exp2f(pxr[j] + ghr));
                const float zg = __builtin_amdgcn_rcpf(1.f + __builtin_amdgcn_exp2f(pxz[j] + ghz));
                const float t1 = ghn + bnc;                          // parallel with rg
                const float an = __builtin_fmaf(rg, t1, pxn[j]);
                const float u  = __builtin_amdgcn_rcpf(1.f + __builtin_amdgcn_exp2f(an));
                const float n  = __builtin_fmaf(-2.f, u, 1.f);       // tanh
                hj = __builtin_fmaf(zg, hj - n, n);                  // (1-z)n + z h
                h_sh[1 - p][c] = (_Float16)hj;                       // write ASAP
                hmax = fmaxf(hmax, hj);
                // refill this slot for step t0+j+4 (consumed 4 step-periods later)
                if (t0 + j + 4 < SS) {
                    const long off = (long)(s + (j + 4) * sstep) * G3;
                    pxr[j] = __builtin_fmaf(gp[off], NL2E, brc);
                    pxz[j] = __builtin_fmaf(gp[off + HH], NL2E, bzc);
                    pxn[j] = gp[off + 2 * HH] * TL2E;
                }
            }
            BAR();
        }
        s += 4 * sstep;
    }
    if (act) pool[(long)b * (2 * HH) + dir * HH + c] = hmax;
}

// ---------------- K4: out[b][o] = fc_b[o] + pool[b,:] . fc_w[o,:]
__global__ __launch_bounds__(256) void k4_fc(const float* __restrict__ pool,
                                             const float* __restrict__ fc_w,
                                             const float* __restrict__ fc_b,
                                             float* __restrict__ out) {
    const int b = blockIdx.x;
    __shared__ __align__(16) float p_sh[2 * HH];
    const int t = threadIdx.x;
    if (t < 2 * HH) p_sh[t] = pool[(long)b * (2 * HH) + t];
    __syncthreads();
    if (t < OUTD) {
        const float4* wr4 = (const float4*)(fc_w + (long)t * (2 * HH));
        const float4* p4 = (const float4*)p_sh;
        float a0 = 0.f, a1 = 0.f;
#pragma unroll
        for (int k = 0; k < 50; k += 2) {
            float4 w0 = wr4[k],   p0 = p4[k];
            float4 w1 = wr4[k+1], p1 = p4[k+1];
            a0 += w0.x*p0.x + w0.y*p0.y + w0.z*p0.z + w0.w*p0.w;
            a1 += w1.x*p1.x + w1.y*p1.y + w1.z*p1.z + w1.w*p1.w;
        }
        out[(long)b * OUTD + t] = fc_b[t] + a0 + a1;
    }
}

extern "C" void kernel_launch(void* const* d_in, const int* in_sizes, int n_in,
                              void* d_out, int out_size, void* d_ws, size_t ws_size,
                              hipStream_t stream) {
    const int*   tok    = (const int*)d_in[0];
    const float* emb    = (const float*)d_in[4];
    const float* w_lin  = (const float*)d_in[5];
    const float* b_lin  = (const float*)d_in[6];
    const float* w_ih_f = (const float*)d_in[7];
    const float* w_hh_f = (const float*)d_in[8];
    const float* b_ih_f = (const float*)d_in[9];
    const float* b_hh_f = (const float*)d_in[10];
    const float* w_ih_b = (const float*)d_in[11];
    const float* w_hh_b = (const float*)d_in[12];
    const float* b_ih_b = (const float*)d_in[13];
    const float* b_hh_b = (const float*)d_in[14];
    const float* fc_w   = (const float*)d_in[15];
    const float* fc_b   = (const float*)d_in[16];

    char* wsb = (char*)d_ws;
    _Float16* wl    = (_Float16*)(wsb);             // 32768 B
    _Float16* k2b   = (_Float16*)(wsb + 32768);     // 163840 B
    _Float16* thi   = (_Float16*)(wsb + 196608);    // 3276800 B
    _Float16* k3b   = (_Float16*)(wsb + 3473408);   // 196608 B
    float*    gx    = (float*)(wsb + 3670016);      // 30720000 B (ends 34.39 MB)
    _Float16* emb16 = (_Float16*)(wsb + 3670016);   // aliases gx: k0->k1 use, k2 overwrites
    float*    pool  = (float*)(wsb);                // aliases wl/k2b: k3 runs after k2
    float*    out   = (float*)d_out;

    k0_prep<<<13 + 3125, 256, 0, stream>>>(w_lin, w_ih_f, w_ih_b, w_hh_f, w_hh_b, emb,
                                           wl, k2b, k3b, emb16);
    k1_mfma<<<NTREE / K1_TPI, 256, 0, stream>>>(tok, emb16, wl, b_lin, thi);
    k2_mfma<<<(NTREE / 32) * 10, 256, 0, stream>>>(thi, k2b, b_ih_f, b_ih_b, gx);
    k3_gru <<<2 * BB, 256, 0, stream>>>(gx, k3b, b_hh_f, b_hh_b, pool);
    k4_fc  <<<BB, 256, 0, stream>>>(pool, fc_w, fc_b, out);
}

// Round 6
// 252.512 us; speedup vs baseline: 1.1589x; 1.1589x over previous
//
#include <hip/hip_runtime.h>
#include <hip/hip_bf16.h>
#include <math.h>

// Problem dims (fixed by reference)
#define BB 64
#define SS 200
#define TT 32
#define VV 50000
#define EE 128
#define CC 128
#define HH 100
#define G3 300           // 3*H
#define OUTD 104
#define NTREE (BB*SS)    // 12800

typedef __attribute__((ext_vector_type(4))) float f32x4;
typedef _Float16 f16x8 __attribute__((ext_vector_type(8)));

#define L2E  1.4426950408889634f
#define NL2E (-1.4426950408889634f)
#define TL2E 2.8853900817779268f

// LDS-only barrier: waits ds-ops (lgkmcnt) but does NOT drain vmcnt, so in-flight
// global prefetch loads stay outstanding across the barrier (waited at use).
#define BAR() asm volatile("s_waitcnt lgkmcnt(0)\n\ts_barrier" ::: "memory")

// Workspace byte offsets
//   wl    @ 0        : 32768 B   (k1 W_lin fragment image, fp16)
//   k2b   @ 32768    : 163840 B  (k2 W_ih fragment image, fp16)
//   thi   @ 196608   : 3276800 B (tree_vec, fp16)
//   k3b   @ 3473408  : 196608 B  (k3 prescaled W_hh fragment image, fp16)
//   gx    @ 3670016  : 30720000 B (fp32)  -- ends at 34.39 MB < ws
//   emb16 @ 3670016  : 12800000 B -- ALIASES gx: k0 writes it, k1 reads it,
//                                   k2 overwrites gx only after k1 completes.
//   pool  @ 0        : 51200 B   -- aliases wl/k2b; k3 writes it AFTER k2 read them.

// ---------------- K0: weight-fragment images + fp16 embedding image (idempotent)
__global__ __launch_bounds__(256) void k0_prep(const float* __restrict__ w_lin,
                                               const float* __restrict__ w_ih_f,
                                               const float* __restrict__ w_ih_b,
                                               const float* __restrict__ w_hh_f,
                                               const float* __restrict__ w_hh_b,
                                               const float* __restrict__ emb,
                                               _Float16* __restrict__ wl,
                                               _Float16* __restrict__ k2b,
                                               _Float16* __restrict__ k3b,
                                               _Float16* __restrict__ emb16) {
    const int tid  = threadIdx.x;
    const int wave = tid >> 6;
    const int lane = tid & 63;
    const int r = lane & 15;
    const int q = lane >> 4;
    if (blockIdx.x == 0) {
        // k1 image: wave w, lane(r,q), nt, kt -> W_lin[n=w*32+nt*16+r][k=kt*32+q*8 ..+8]
#pragma unroll
        for (int nt = 0; nt < 2; ++nt)
#pragma unroll
            for (int kt = 0; kt < 4; ++kt) {
                const int n = wave * 32 + nt * 16 + r;
                const float* src = w_lin + (long)n * EE + kt * 32 + q * 8;
                f16x8 f;
#pragma unroll
                for (int e = 0; e < 8; ++e) f[e] = (_Float16)src[e];
                *(f16x8*)&wl[(size_t)((((wave * 2 + nt) * 4 + kt) * 64) + lane) * 8] = f;
            }
    } else if (blockIdx.x <= 10) {
        // k2 image: nb, wave w, lane(r,q), kt -> W_ih[padded n = nb*64+w*16+r][k=kt*32+q*8]
        const int nb = blockIdx.x - 1;           // 0..9
        const int n = nb * 64 + wave * 16 + r;
        const int dir = (n >= 320) ? 1 : 0;
        const int j = n - dir * 320;
        const int jj = (j < G3) ? j : 0;         // pad rows clamped (results discarded)
        const float* w = dir ? w_ih_b : w_ih_f;
#pragma unroll
        for (int kt = 0; kt < 4; ++kt) {
            const float* src = w + (long)jj * EE + kt * 32 + q * 8;
            f16x8 f;
#pragma unroll
            for (int e = 0; e < 8; ++e) f[e] = (_Float16)src[e];
            *(f16x8*)&k2b[(size_t)((((nb * 4 + wave) * 4 + kt) * 64) + lane) * 8] = f;
        }
    } else if (blockIdx.x <= 12) {
        // k3 image, PRESCALED: dir d, wave-slot w (channels 25w..25w+24).
        // 6 tiles: t in 0..2 -> gate t of within-wave channel r; t in 3..5 -> gate
        // t-3 of channel 16+r (valid iff <25). Gates r,z scaled by -log2(e); gate n
        // scaled by +2*log2(e) (folds the exp2 arguments of sigmoid/tanh).
        const int d = blockIdx.x - 11;           // 0..1
        const float* whh = d ? w_hh_b : w_hh_f;
#pragma unroll
        for (int t = 0; t < 6; ++t) {
            const int gate = (t < 3) ? t : t - 3;
            const int ch   = (t < 3) ? r : 16 + r;
            const bool nv  = (ch < 25);
            const int row  = gate * HH + wave * 25 + (nv ? ch : 0);
            const float sc = (gate == 2) ? TL2E : NL2E;
#pragma unroll
            for (int kt = 0; kt < 4; ++kt) {
                f16x8 f;
#pragma unroll
                for (int e = 0; e < 8; ++e) {
                    const int k = kt * 32 + q * 8 + e;
                    f[e] = (_Float16)((nv && k < HH) ? sc * whh[row * HH + k] : 0.f);
                }
                *(f16x8*)&k3b[(size_t)((((d * 4 + wave) * 6 + t) * 4 + kt) * 64 + lane) * 8] = f;
            }
        }
    } else {
        // fp16 embedding image: 50000*128 = 6,400,000 elems = 3125 blocks * 2048
        const long base = (long)(blockIdx.x - 13) * 2048 + (long)tid * 8;
        if (base < (long)VV * EE) {
            const float4* s = (const float4*)(emb + base);
            const float4 v0 = s[0], v1 = s[1];
            f16x8 f;
            f[0] = (_Float16)v0.x; f[1] = (_Float16)v0.y;
            f[2] = (_Float16)v0.z; f[3] = (_Float16)v0.w;
            f[4] = (_Float16)v1.x; f[5] = (_Float16)v1.y;
            f[6] = (_Float16)v1.z; f[7] = (_Float16)v1.w;
            *(f16x8*)&emb16[base] = f;
        }
    }
}

// ---------------- K1 (fp16 MFMA): embed-gather (fp16) -> GEMM vs W_lin^T -> bias -> tree-sum -> maxpool
#define K1_TPI 2
#define AROWS (K1_TPI*TT)        // 64
#define LDA 136                  // fp16/row: 128 + 8 pad
#define LDC 132                  // fp32/row: 128 + 4 pad

__global__ __launch_bounds__(256) void k1_mfma(const int* __restrict__ tok,
                                               const _Float16* __restrict__ emb16,
                                               const _Float16* __restrict__ wl,
                                               const float* __restrict__ b_lin,
                                               _Float16* __restrict__ thi) {
    __shared__ __align__(16) _Float16 A_sh[AROWS * LDA];   // 17408 B
    __shared__ __align__(16) float C_sh[AROWS * LDC];      // 33792 B
    __shared__ int tok_sh[AROWS];

    const int tid  = threadIdx.x;
    const int wave = tid >> 6;
    const int lane = tid & 63;
    const int r = lane & 15;
    const int q = lane >> 4;

    // ---- B fragments: 8 coalesced 16B loads from the prebuilt image (no cvt VALU)
    f16x8 bfrag[2][4];
    float bias[2];
#pragma unroll
    for (int nt = 0; nt < 2; ++nt) {
        bias[nt] = b_lin[wave * 32 + nt * 16 + r];
#pragma unroll
        for (int kt = 0; kt < 4; ++kt)
            bfrag[nt][kt] = *(const f16x8*)&wl[(size_t)((((wave * 2 + nt) * 4 + kt) * 64) + lane) * 8];
    }

    const int tree0 = blockIdx.x * K1_TPI;
    if (tid < AROWS) tok_sh[tid] = tok[tree0 * TT + tid];
    __syncthreads();

    // ---- gather fp16 embeddings -> LDS (pure 16B copies, half the global traffic)
#pragma unroll
    for (int i = 0; i < 4; ++i) {
        const int idx = tid + i * 256;       // 0..1023
        const int row = idx >> 4;            // 64 rows
        const int p   = idx & 15;            // 16 x f16x8 = 128 elems
        const f16x8 v = *(const f16x8*)&emb16[(long)tok_sh[row] * EE + p * 8];
        *(f16x8*)&A_sh[row * LDA + p * 8] = v;
    }
    __syncthreads();

    f32x4 acc[4][2];
#pragma unroll
    for (int mt = 0; mt < 4; ++mt)
#pragma unroll
        for (int nt = 0; nt < 2; ++nt) acc[mt][nt] = (f32x4)(0.f);

#pragma unroll
    for (int mt = 0; mt < 4; ++mt) {
        const int m = mt * 16 + r;
        f16x8 afrag[4];
#pragma unroll
        for (int kt = 0; kt < 4; ++kt)
            afrag[kt] = *(const f16x8*)&A_sh[m * LDA + kt * 32 + q * 8];
#pragma unroll
        for (int nt = 0; nt < 2; ++nt)
#pragma unroll
            for (int kt = 0; kt < 4; ++kt)
                acc[mt][nt] = __builtin_amdgcn_mfma_f32_16x16x32_f16(
                    afrag[kt], bfrag[nt][kt], acc[mt][nt], 0, 0, 0);
    }

#pragma unroll
    for (int mt = 0; mt < 4; ++mt)
#pragma unroll
        for (int nt = 0; nt < 2; ++nt) {
            const int col = wave * 32 + nt * 16 + r;
#pragma unroll
            for (int reg = 0; reg < 4; ++reg) {
                const int row = mt * 16 + q * 4 + reg;
                C_sh[row * LDC + col] = acc[mt][nt][reg] + bias[nt];
            }
        }
    __syncthreads();

    // ---- tree-sum + maxpool in registers (descending index = topological order)
    {
        const int t = tid >> 7;
        const int j = tid & 127;
        const float* base = &C_sh[(t * TT) * LDC + j];
        float v[TT];
#pragma unroll
        for (int n = 0; n < TT; ++n) v[n] = base[n * LDC];
        float mx = -1e30f;
#pragma unroll
        for (int n = TT - 1; n >= 1; --n) {
            mx = fmaxf(mx, v[n]);
            v[(n - 1) >> 1] += v[n];
        }
        mx = fmaxf(mx, v[0]);
        thi[(size_t)(tree0 + t) * CC + j] = (_Float16)mx;   // fp32 sums, one fp16 round
    }
}

// ---------------- K2 (fp16 MFMA): gx[dir][m=b*S+s][300] = X @ W_ih^T + b_ih
__global__ __launch_bounds__(256) void k2_mfma(const _Float16* __restrict__ thi,
                                               const _Float16* __restrict__ k2b,
                                               const float* __restrict__ b_ih_f,
                                               const float* __restrict__ b_ih_b,
                                               float* __restrict__ gx) {
    __shared__ __align__(16) _Float16 Ah[32 * LDA];   // 8704 B

    const int tid  = threadIdx.x;
    const int wave = tid >> 6;
    const int lane = tid & 63;
    const int r = lane & 15;
    const int q = lane >> 4;

    const int nb = blockIdx.x % 10;
    const int mb = blockIdx.x / 10;
    const int m0 = mb * 32;
    const int n0 = nb * 64;

    // stage A: 32 rows x 128 fp16 = 512 f16x8; 2 per thread (copy, no conversion)
#pragma unroll
    for (int i = 0; i < 2; ++i) {
        const int idx = tid + i * 256;
        const int row = idx >> 4;
        const int p   = idx & 15;
        f16x8 v = *(const f16x8*)&thi[(size_t)(m0 + row) * CC + p * 8];
        *(f16x8*)&Ah[row * LDA + p * 8] = v;
    }
    // B fragments: 4 coalesced 16B loads
    f16x8 bh[4];
#pragma unroll
    for (int kt = 0; kt < 4; ++kt)
        bh[kt] = *(const f16x8*)&k2b[(size_t)((((nb * 4 + wave) * 4 + kt) * 64) + lane) * 8];
    __syncthreads();

    f32x4 acc[2];
    acc[0] = (f32x4)(0.f); acc[1] = (f32x4)(0.f);
#pragma unroll
    for (int mt = 0; mt < 2; ++mt) {
        const int m = mt * 16 + r;
#pragma unroll
        for (int kt = 0; kt < 4; ++kt) {
            f16x8 a = *(const f16x8*)&Ah[m * LDA + kt * 32 + q * 8];
            acc[mt] = __builtin_amdgcn_mfma_f32_16x16x32_f16(a, bh[kt], acc[mt], 0, 0, 0);
        }
    }

    const int ng  = n0 + wave * 16 + r;
    const int dir = (ng >= 320) ? 1 : 0;
    const int j   = ng - dir * 320;
    const bool valid = (j < G3);
    const float bias = valid ? (dir ? b_ih_b[j] : b_ih_f[j]) : 0.f;
    float* gxd = gx + (long)dir * NTREE * G3;
    if (valid) {
#pragma unroll
        for (int mt = 0; mt < 2; ++mt)
#pragma unroll
            for (int reg = 0; reg < 4; ++reg) {
                const int m = m0 + mt * 16 + q * 4 + reg;
                gxd[(long)m * G3 + j] = acc[mt][reg] + bias;
            }
    }
}

// ---------------- K3 v11: v10 with PURE prefetch restored.
// v10's regression (133.6 us vs v7's 88.5) was the prescale FMA folded into the
// prefetch refill: pxr[j]=fma(load,...) made the refill depend on the loaded value,
// forcing s_waitcnt vmcnt in the SAME iteration as the issue -- the 4-deep pipeline
// collapsed to depth 0 (exactly the v5/v6 bug, reintroduced). RULE: the prefetch
// slot receives the RAW load, untouched; all scale/bias math happens at consumption
// where it schedules into the MFMA shadow (load-independent of MFMA results).
__global__ __launch_bounds__(256, 1) void k3_gru(const float* __restrict__ gx,
                                                 const _Float16* __restrict__ k3b,
                                                 const float* __restrict__ b_hh_f,
                                                 const float* __restrict__ b_hh_b,
                                                 float* __restrict__ pool) {
    const int bid = blockIdx.x;   // 0..127
    const int dir = bid & 1;
    const int b   = bid >> 1;
    const int tid = threadIdx.x;
    const int wave = tid >> 6;
    const int lane = tid & 63;
    const int r = lane & 15;
    const int q = lane >> 4;

    const float* b_hh = dir ? b_hh_b : b_hh_f;

    __shared__ __align__(16) _Float16 h_sh[2][128];

    // B fragments: 24 coalesced 16B loads from the prebuilt PRESCALED image
    const int dw = dir * 4 + wave;
    f16x8 bf[6][4];
#pragma unroll
    for (int t = 0; t < 6; ++t)
#pragma unroll
        for (int kt = 0; kt < 4; ++kt)
            bf[t][kt] = *(const f16x8*)&k3b[(size_t)(((dw * 6 + t) * 4 + kt) * 64 + lane) * 8];

    const int m = lane;
    const int c = wave * 25 + m;
    const bool act  = (m < 25);
    const bool lo16 = (m < 16);
    // prescaled biases (match the weight-image scales)
    float brc = 0.f, bzc = 0.f, bnc = 0.f;
    if (act) {
        brc = NL2E * b_hh[c];
        bzc = NL2E * b_hh[HH + c];
        bnc = TL2E * b_hh[2 * HH + c];
    }

    if (tid < 128) { h_sh[0][tid] = (_Float16)0.f; h_sh[1][tid] = (_Float16)0.f; }

    const int sstep = dir ? -1 : 1;
    const int s0 = dir ? (SS - 1) : 0;
    const float* gp = gx + (long)dir * NTREE * G3 + (long)b * SS * G3 + c;

    // 4-deep prefetch, NAMED buffers, RAW loads only (no dependent math here!)
    float pxr[4], pxz[4], pxn[4];
    if (act) {
#pragma unroll
        for (int j = 0; j < 4; ++j) {
            const long off = (long)(s0 + j * sstep) * G3;
            pxr[j] = gp[off]; pxz[j] = gp[off + HH]; pxn[j] = gp[off + 2 * HH];
        }
    }
    float hj = 0.f, hmax = -1e30f;
    __syncthreads();

    int s = s0;
    for (int t0 = 0; t0 < SS; t0 += 4) {
#pragma unroll
        for (int j = 0; j < 4; ++j) {
            const int p = j & 1;             // (t0+j)&1, t0 multiple of 4

            f16x8 a[4];
#pragma unroll
            for (int kt = 0; kt < 4; ++kt)
                a[kt] = *(const f16x8*)&h_sh[p][kt * 32 + q * 8];

            // consumption-side prescale: independent of MFMA results, schedules
            // into the MFMA shadow (right after the vmcnt wait for slot j)
            const float xr = __builtin_fmaf(pxr[j], NL2E, brc);
            const float xz = __builtin_fmaf(pxz[j], NL2E, bzc);
            const float xn = pxn[j] * TL2E;

            // split-K: two parallel depth-2 chains per tile, 24 MFMA total
            f32x4 accA[6], accB[6];
#pragma unroll
            for (int i = 0; i < 6; ++i) {
                accA[i] = (f32x4)(0.f);
                accB[i] = (f32x4)(0.f);
                accA[i] = __builtin_amdgcn_mfma_f32_16x16x32_f16(a[0], bf[i][0], accA[i], 0, 0, 0);
                accB[i] = __builtin_amdgcn_mfma_f32_16x16x32_f16(a[2], bf[i][2], accB[i], 0, 0, 0);
                accA[i] = __builtin_amdgcn_mfma_f32_16x16x32_f16(a[1], bf[i][1], accA[i], 0, 0, 0);
                accB[i] = __builtin_amdgcn_mfma_f32_16x16x32_f16(a[3], bf[i][3], accB[i], 0, 0, 0);
            }
            const float G0 = accA[0][0] + accB[0][0];
            const float G1 = accA[1][0] + accB[1][0];
            const float G2 = accA[2][0] + accB[2][0];
            const float G3v = accA[3][0] + accB[3][0];
            const float G4 = accA[4][0] + accB[4][0];
            const float G5 = accA[5][0] + accB[5][0];
            // lane m<16: gates of channel m via tiles 0-2; m in 16..24: tiles 3-5
            const float ghr = lo16 ? G0 : G3v;
            const float ghz = lo16 ? G1 : G4;
            const float ghn = lo16 ? G2 : G5;

            if (act) {
                const float rg = __builtin_amdgcn_rcpf(1.f + __builtin_amdgcn_exp2f(xr + ghr));
                const float zg = __builtin_amdgcn_rcpf(1.f + __builtin_amdgcn_exp2f(xz + ghz));
                const float t1 = ghn + bnc;                          // parallel with rg
                const float an = __builtin_fmaf(rg, t1, xn);
                const float u  = __builtin_amdgcn_rcpf(1.f + __builtin_amdgcn_exp2f(an));
                const float n  = __builtin_fmaf(-2.f, u, 1.f);       // tanh
                hj = __builtin_fmaf(zg, hj - n, n);                  // (1-z)n + z h
                h_sh[1 - p][c] = (_Float16)hj;                       // write ASAP
                hmax = fmaxf(hmax, hj);
                // refill slot j for step t0+j+4: RAW loads, no dependent ops
                if (t0 + j + 4 < SS) {
                    const long off = (long)(s + (j + 4) * sstep) * G3;
                    pxr[j] = gp[off]; pxz[j] = gp[off + HH]; pxn[j] = gp[off + 2 * HH];
                }
            }
            BAR();
        }
        s += 4 * sstep;
    }
    if (act) pool[(long)b * (2 * HH) + dir * HH + c] = hmax;
}

// ---------------- K4: out[b][o] = fc_b[o] + pool[b,:] . fc_w[o,:]
__global__ __launch_bounds__(256) void k4_fc(const float* __restrict__ pool,
                                             const float* __restrict__ fc_w,
                                             const float* __restrict__ fc_b,
                                             float* __restrict__ out) {
    const int b = blockIdx.x;
    __shared__ __align__(16) float p_sh[2 * HH];
    const int t = threadIdx.x;
    if (t < 2 * HH) p_sh[t] = pool[(long)b * (2 * HH) + t];
    __syncthreads();
    if (t < OUTD) {
        const float4* wr4 = (const float4*)(fc_w + (long)t * (2 * HH));
        const float4* p4 = (const float4*)p_sh;
        float a0 = 0.f, a1 = 0.f;
#pragma unroll
        for (int k = 0; k < 50; k += 2) {
            float4 w0 = wr4[k],   p0 = p4[k];
            float4 w1 = wr4[k+1], p1 = p4[k+1];
            a0 += w0.x*p0.x + w0.y*p0.y + w0.z*p0.z + w0.w*p0.w;
            a1 += w1.x*p1.x + w1.y*p1.y + w1.z*p1.z + w1.w*p1.w;
        }
        out[(long)b * OUTD + t] = fc_b[t] + a0 + a1;
    }
}

extern "C" void kernel_launch(void* const* d_in, const int* in_sizes, int n_in,
                              void* d_out, int out_size, void* d_ws, size_t ws_size,
                              hipStream_t stream) {
    const int*   tok    = (const int*)d_in[0];
    const float* emb    = (const float*)d_in[4];
    const float* w_lin  = (const float*)d_in[5];
    const float* b_lin  = (const float*)d_in[6];
    const float* w_ih_f = (const float*)d_in[7];
    const float* w_hh_f = (const float*)d_in[8];
    const float* b_ih_f = (const float*)d_in[9];
    const float* b_hh_f = (const float*)d_in[10];
    const float* w_ih_b = (const float*)d_in[11];
    const float* w_hh_b = (const float*)d_in[12];
    const float* b_ih_b = (const float*)d_in[13];
    const float* b_hh_b = (const float*)d_in[14];
    const float* fc_w   = (const float*)d_in[15];
    const float* fc_b   = (const float*)d_in[16];

    char* wsb = (char*)d_ws;
    _Float16* wl    = (_Float16*)(wsb);             // 32768 B
    _Float16* k2b   = (_Float16*)(wsb + 32768);     // 163840 B
    _Float16* thi   = (_Float16*)(wsb + 196608);    // 3276800 B
    _Float16* k3b   = (_Float16*)(wsb + 3473408);   // 196608 B
    float*    gx    = (float*)(wsb + 3670016);      // 30720000 B (ends 34.39 MB)
    _Float16* emb16 = (_Float16*)(wsb + 3670016);   // aliases gx: k0->k1 use, k2 overwrites
    float*    pool  = (float*)(wsb);                // aliases wl/k2b: k3 runs after k2
    float*    out   = (float*)d_out;

    k0_prep<<<13 + 3125, 256, 0, stream>>>(w_lin, w_ih_f, w_ih_b, w_hh_f, w_hh_b, emb,
                                           wl, k2b, k3b, emb16);
    k1_mfma<<<NTREE / K1_TPI, 256, 0, stream>>>(tok, emb16, wl, b_lin, thi);
    k2_mfma<<<(NTREE / 32) * 10, 256, 0, stream>>>(thi, k2b, b_ih_f, b_ih_b, gx);
    k3_gru <<<2 * BB, 256, 0, stream>>>(gx, k3b, b_hh_f, b_hh_b, pool);
    k4_fc  <<<BB, 256, 0, stream>>>(pool, fc_w, fc_b, out);
}